// Round 8
// baseline (7926.320 us; speedup 1.0000x reference)
//
#include <hip/hip_runtime.h>

#define NB 32
#define NT 128
#define NU 768
#define ND 768
#define UPB 3
#define NBLK 256          // one block per CU
#define NTHR 768          // 12 waves/CU
#define HPAD 772          // sh row stride (float), 16B-aligned

#define AGENT __HIP_MEMORY_SCOPE_AGENT

typedef float f32x2 __attribute__((ext_vector_type(2)));
typedef float f32x4 __attribute__((ext_vector_type(4)));

__device__ __forceinline__ float fexp2(float x) { return __builtin_amdgcn_exp2f(x); }
__device__ __forceinline__ float frcp(float x)  { return __builtin_amdgcn_rcpf(x); }

// x[B,T,D] -> x4[t][d4][b][4]   (dwordx4-per-(d4,b) layout)
__global__ void make_x4_kernel(const float* __restrict__ x, float* __restrict__ x4) {
  const int t = blockIdx.x;        // 0..127
  const int g = blockIdx.y;        // 0..5 (32 d4's each)
  const size_t obase = ((size_t)t * 192 + g * 32) * 128;
#pragma unroll
  for (int i = 0; i < 16; ++i) {
    int o = i * 256 + threadIdx.x;          // contiguous writes
    int d4l = o >> 7, b = (o >> 2) & 31, j = o & 3;
    x4[obase + o] = x[((size_t)b * NT + t) * ND + (g * 32 + d4l) * 4 + j];
  }
}

__global__ void init_flags_kernel(unsigned int* __restrict__ flags) {
  flags[threadIdx.x] = 0u;   // d_ws is 0xAA-poisoned each launch; must zero
}

// outT[T,U,B] -> out[B,T,U]
__global__ void transpose_out_kernel(const float* __restrict__ outT, float* __restrict__ out) {
  __shared__ float tile[32][33];
  const int t  = blockIdx.x;
  const int u0 = blockIdx.y * 32;
  const int lo = threadIdx.x & 31;
  const int hi = threadIdx.x >> 5;
#pragma unroll
  for (int uu = hi; uu < 32; uu += 8)
    tile[uu][lo] = outT[((size_t)t * NU + u0 + uu) * NB + lo];
  __syncthreads();
#pragma unroll
  for (int bb = hi; bb < 32; bb += 8)
    out[((size_t)bb * NT + t) * NU + u0 + lo] = tile[lo][bb];
}

__global__ void __launch_bounds__(NTHR, 3)
rnn_fused_kernel(const float* __restrict__ x4,
                 const float* __restrict__ wk,
                 const float* __restrict__ wrk,
                 const float* __restrict__ wak,
                 const float* __restrict__ wrak,
                 const float* __restrict__ bias,
                 const float* __restrict__ gpa,
                 const float* __restrict__ gpra,
                 const float* __restrict__ h0,   // [B,U] = [b][u], read directly at t=0
                 float* hA, float* hB,           // ping-pong, [b][u]
                 float* __restrict__ outT,
                 unsigned int* flags)
{
  const int tid  = threadIdx.x;
  const int uloc = tid >> 8;       // 0..2
  const int lt   = tid & 255;
  const int b    = lt & 15;        // handles b and b+16
  const int c    = lt >> 4;        // 0..15 chunk of 48 d
  const int d0   = c * 48;
  const int u    = blockIdx.x * UPB + uloc;

  __shared__ __align__(16) float s_ak[UPB][ND], s_k[UPB][ND], s_rak[UPB][ND], s_rk[UPB][ND];
  __shared__ __align__(16) float sh[NB][HPAD];     // staged h, [b][u]
  __shared__ float red[UPB][12][4][16];
  __shared__ float s_hu[UPB][NB];                  // block-local h for own u's

#pragma unroll
  for (int j = 0; j < UPB; ++j) {
    const int ug = blockIdx.x * UPB + j;
    s_ak [j][tid] = wak [(size_t)ug * ND + tid];
    s_k  [j][tid] = wk  [(size_t)ug * ND + tid];
    s_rak[j][tid] = wrak[(size_t)ug * NU + tid];
    s_rk [j][tid] = wrk [(size_t)ug * NU + tid];
  }
  if (tid < UPB * NB) {
    const int uj = tid >> 5, bj = tid & 31;
    s_hu[uj][bj] = h0[(size_t)bj * NU + blockIdx.x * UPB + uj];
  }
  const float bias_u = bias[u];
  const float ga  = 1.0f / (1.0f + __expf(-gpa[0]));
  const float gra = 1.0f / (1.0f + __expf(-gpra[0]));
  __syncthreads();

  const float* hcur = h0;
  float* hnext  = hB;
  float* hspare = hA;
  const float LOG2E = 1.4426950408889634f;
  const int q = tid / 192;             // stage row base: b = 4r + q
  const int s = tid - q * 192;         // stage col: u = 4s

  for (int t = 0; t < NT; ++t) {
    // ---- wait for step-t h to be published ----
    if (t > 0) {
      if (tid < NBLK) {
        const unsigned tgt = (unsigned)t;
        while (__hip_atomic_load(&flags[tid], __ATOMIC_RELAXED, AGENT) < tgt)
          __builtin_amdgcn_s_sleep(2);
      }
      __syncthreads();
    }

    // ---- issue h stage loads (compiler-scheduled; land during x-half) ----
    const double* hq = (const double*)hcur;
    double hd0[8], hd1[8];
#pragma unroll
    for (int r = 0; r < 8; ++r) {
      hd0[r] = __hip_atomic_load(hq + 1536 * r + 2 * tid,     __ATOMIC_RELAXED, AGENT);
      hd1[r] = __hip_atomic_load(hq + 1536 * r + 2 * tid + 1, __ATOMIC_RELAXED, AGENT);
    }

    // ---- x-half: needs only block-local hu ----
    const float huA = s_hu[uloc][b];
    const float huB = s_hu[uloc][b + 16];
    const float hsA = huA * LOG2E, hsB = huB * LOG2E;
    const f32x4 hsA4 = {hsA, hsA, hsA, hsA};
    const f32x4 hsB4 = {hsB, hsB, hsB, hsB};

    f32x4 saA = {0,0,0,0}, naA = {0,0,0,0}, laA = {0,0,0,0};
    f32x4 saB = {0,0,0,0}, naB = {0,0,0,0}, laB = {0,0,0,0};
    const f32x4* xp = (const f32x4*)x4 + (((size_t)t * 192 + c * 12) * 32 + b);
#pragma unroll
    for (int k4 = 0; k4 < 12; ++k4) {
      const f32x4 av  = *(const f32x4*)&s_ak[uloc][d0 + 4 * k4];
      const f32x4 kv  = *(const f32x4*)&s_k [uloc][d0 + 4 * k4];
      const f32x4 xvA = xp[k4 * 32];
      const f32x4 xvB = xp[k4 * 32 + 16];
      f32x4 tA = (xvA * av) * hsA4;
      f32x4 tB = (xvB * av) * hsB4;
      f32x4 eA = {fexp2(tA.x), fexp2(tA.y), fexp2(tA.z), fexp2(tA.w)};
      f32x4 eB = {fexp2(tB.x), fexp2(tB.y), fexp2(tB.z), fexp2(tB.w)};
      f32x4 kxA = kv * xvA;
      f32x4 kxB = kv * xvB;
      saA += eA; laA += kxA; naA += eA * kxA;
      saB += eB; laB += kxB; naB += eB * kxB;
    }

    // ---- commit staged h to LDS (first use of hd*: compiler places the wait here) ----
#pragma unroll
    for (int r = 0; r < 8; ++r) {
      const f32x2 lo = __builtin_bit_cast(f32x2, hd0[r]);
      const f32x2 hi = __builtin_bit_cast(f32x2, hd1[r]);
      const f32x4 v = {lo.x, lo.y, hi.x, hi.y};
      *(f32x4*)&sh[q + 4 * r][s * 4] = v;
    }
    __syncthreads();

    // ---- r-half: h from LDS ----
    f32x4 srA = {0,0,0,0}, nrA = {0,0,0,0}, lrA = {0,0,0,0};
    f32x4 srB = {0,0,0,0}, nrB = {0,0,0,0}, lrB = {0,0,0,0};
#pragma unroll
    for (int k4 = 0; k4 < 12; ++k4) {
      const f32x4 rav = *(const f32x4*)&s_rak[uloc][d0 + 4 * k4];
      const f32x4 rkv = *(const f32x4*)&s_rk [uloc][d0 + 4 * k4];
      const f32x4 hvA = *(const f32x4*)&sh[b][d0 + 4 * k4];
      const f32x4 hvB = *(const f32x4*)&sh[b + 16][d0 + 4 * k4];
      f32x4 rtA = (hvA * rav) * hsA4;
      f32x4 rtB = (hvB * rav) * hsB4;
      f32x4 reA = {fexp2(rtA.x), fexp2(rtA.y), fexp2(rtA.z), fexp2(rtA.w)};
      f32x4 reB = {fexp2(rtB.x), fexp2(rtB.y), fexp2(rtB.z), fexp2(rtB.w)};
      f32x4 khA = rkv * hvA;
      f32x4 khB = rkv * hvB;
      srA += reA; lrA += khA; nrA += reA * khA;
      srB += reB; lrB += khB; nrB += reB * khB;
    }

    // ---- horizontal collapse + 16-chunk reduction ----
    float v0  = saA.x + saA.y + saA.z + saA.w;
    float v1  = naA.x + naA.y + naA.z + naA.w;
    float v2  = laA.x + laA.y + laA.z + laA.w;
    float v3  = srA.x + srA.y + srA.z + srA.w;
    float v4  = nrA.x + nrA.y + nrA.z + nrA.w;
    float v5  = lrA.x + lrA.y + lrA.z + lrA.w;
    float v6  = saB.x + saB.y + saB.z + saB.w;
    float v7  = naB.x + naB.y + naB.z + naB.w;
    float v8  = laB.x + laB.y + laB.z + laB.w;
    float v9  = srB.x + srB.y + srB.z + srB.w;
    float v10 = nrB.x + nrB.y + nrB.z + nrB.w;
    float v11 = lrB.x + lrB.y + lrB.z + lrB.w;

    v0  += __shfl_xor(v0, 16);  v0  += __shfl_xor(v0, 32);
    v1  += __shfl_xor(v1, 16);  v1  += __shfl_xor(v1, 32);
    v2  += __shfl_xor(v2, 16);  v2  += __shfl_xor(v2, 32);
    v3  += __shfl_xor(v3, 16);  v3  += __shfl_xor(v3, 32);
    v4  += __shfl_xor(v4, 16);  v4  += __shfl_xor(v4, 32);
    v5  += __shfl_xor(v5, 16);  v5  += __shfl_xor(v5, 32);
    v6  += __shfl_xor(v6, 16);  v6  += __shfl_xor(v6, 32);
    v7  += __shfl_xor(v7, 16);  v7  += __shfl_xor(v7, 32);
    v8  += __shfl_xor(v8, 16);  v8  += __shfl_xor(v8, 32);
    v9  += __shfl_xor(v9, 16);  v9  += __shfl_xor(v9, 32);
    v10 += __shfl_xor(v10, 16); v10 += __shfl_xor(v10, 32);
    v11 += __shfl_xor(v11, 16); v11 += __shfl_xor(v11, 32);

    const int w = (tid >> 6) & 3;
    if ((tid & 63) < 16) {
      red[uloc][0][w][b] = v0;   red[uloc][1][w][b] = v1;   red[uloc][2][w][b] = v2;
      red[uloc][3][w][b] = v3;   red[uloc][4][w][b] = v4;   red[uloc][5][w][b] = v5;
      red[uloc][6][w][b] = v6;   red[uloc][7][w][b] = v7;   red[uloc][8][w][b] = v8;
      red[uloc][9][w][b] = v9;   red[uloc][10][w][b] = v10; red[uloc][11][w][b] = v11;
    }
    __syncthreads();

    if (lt < 16) {
      float r0  = red[uloc][0][0][lt]  + red[uloc][0][1][lt]  + red[uloc][0][2][lt]  + red[uloc][0][3][lt];
      float r1  = red[uloc][1][0][lt]  + red[uloc][1][1][lt]  + red[uloc][1][2][lt]  + red[uloc][1][3][lt];
      float r2  = red[uloc][2][0][lt]  + red[uloc][2][1][lt]  + red[uloc][2][2][lt]  + red[uloc][2][3][lt];
      float r3  = red[uloc][3][0][lt]  + red[uloc][3][1][lt]  + red[uloc][3][2][lt]  + red[uloc][3][3][lt];
      float r4  = red[uloc][4][0][lt]  + red[uloc][4][1][lt]  + red[uloc][4][2][lt]  + red[uloc][4][3][lt];
      float r5  = red[uloc][5][0][lt]  + red[uloc][5][1][lt]  + red[uloc][5][2][lt]  + red[uloc][5][3][lt];
      float r6  = red[uloc][6][0][lt]  + red[uloc][6][1][lt]  + red[uloc][6][2][lt]  + red[uloc][6][3][lt];
      float r7  = red[uloc][7][0][lt]  + red[uloc][7][1][lt]  + red[uloc][7][2][lt]  + red[uloc][7][3][lt];
      float r8  = red[uloc][8][0][lt]  + red[uloc][8][1][lt]  + red[uloc][8][2][lt]  + red[uloc][8][3][lt];
      float r9  = red[uloc][9][0][lt]  + red[uloc][9][1][lt]  + red[uloc][9][2][lt]  + red[uloc][9][3][lt];
      float r10 = red[uloc][10][0][lt] + red[uloc][10][1][lt] + red[uloc][10][2][lt] + red[uloc][10][3][lt];
      float r11 = red[uloc][11][0][lt] + red[uloc][11][1][lt] + red[uloc][11][2][lt] + red[uloc][11][3][lt];

      float hhA = r2 + bias_u + ga * (r1 * frcp(r0));
      float zA  = hhA + r5 + gra * (r4 * frcp(r3));
      float exA = fexp2(zA * 2.8853900817779268f);   // tanh(z) = 1 - 2/(e^{2z}+1)
      float oA  = 1.0f - 2.0f * frcp(exA + 1.0f);
      float hhB = r8 + bias_u + ga * (r7 * frcp(r6));
      float zB  = hhB + r11 + gra * (r10 * frcp(r9));
      float exB = fexp2(zB * 2.8853900817779268f);
      float oB  = 1.0f - 2.0f * frcp(exB + 1.0f);

      __hip_atomic_store(&hnext[(size_t)lt * NU + u],        oA, __ATOMIC_RELAXED, AGENT);
      __hip_atomic_store(&hnext[(size_t)(lt + 16) * NU + u], oB, __ATOMIC_RELAXED, AGENT);
      outT[((size_t)t * NU + u) * NB + lt]      = oA;
      outT[((size_t)t * NU + u) * NB + lt + 16] = oB;
      s_hu[uloc][lt]      = oA;    // local broadcast for next step's x-half
      s_hu[uloc][lt + 16] = oB;
    }

    if (t != NT - 1) {
      asm volatile("s_waitcnt vmcnt(0)" ::: "memory");
      __syncthreads();   // all waves' h-stores drained; s_hu visible
      if (tid == 0)
        __hip_atomic_store(&flags[blockIdx.x], (unsigned)(t + 1), __ATOMIC_RELAXED, AGENT);
    }
    float* nn = (t == 0) ? hspare : (float*)hcur;
    hcur = hnext; hnext = nn;
  }
}

extern "C" void kernel_launch(void* const* d_in, const int* in_sizes, int n_in,
                              void* d_out, int out_size, void* d_ws, size_t ws_size,
                              hipStream_t stream) {
  const float* x    = (const float*)d_in[0];
  const float* h0   = (const float*)d_in[1];
  const float* wk   = (const float*)d_in[2];
  const float* wrk  = (const float*)d_in[3];
  const float* wak  = (const float*)d_in[4];
  const float* wrak = (const float*)d_in[5];
  const float* bias = (const float*)d_in[6];
  const float* gpa  = (const float*)d_in[7];
  const float* gpra = (const float*)d_in[8];
  float* out = (float*)d_out;

  float* x4   = (float*)d_ws;                       // 12.58 MB
  float* outT = x4 + (size_t)NT * ND * NB;          // 12.58 MB
  float* hA   = outT + (size_t)NT * NU * NB;        // 96 KB
  float* hB   = hA + NU * NB;                       // 96 KB
  unsigned int* flags = (unsigned int*)(hB + NU * NB);

  make_x4_kernel<<<dim3(NT, 6), 256, 0, stream>>>(x, x4);
  init_flags_kernel<<<1, 256, 0, stream>>>(flags);
  rnn_fused_kernel<<<NBLK, NTHR, 0, stream>>>(x4, wk, wrk, wak, wrak, bias, gpa, gpra,
                                              h0, hA, hB, outT, flags);
  transpose_out_kernel<<<dim3(NT, NU / 32), 256, 0, stream>>>(outT, out);
}

// Round 9
// 3354.414 us; speedup vs baseline: 2.3630x; 2.3630x over previous
//
#include <hip/hip_runtime.h>

#define NB 32
#define NT 128
#define NU 768
#define ND 768
#define UPB 3
#define NBLK 256          // one block per CU
#define NTHR 768          // 12 waves/CU

#define AGENT __HIP_MEMORY_SCOPE_AGENT

typedef float f32x4 __attribute__((ext_vector_type(4)));

__device__ __forceinline__ float fexp2(float x) { return __builtin_amdgcn_exp2f(x); }
__device__ __forceinline__ float frcp(float x)  { return __builtin_amdgcn_rcpf(x); }

// x[B,T,D] -> x4[t][d4][b][4]   (dwordx4-per-(d4,b) layout)
__global__ void make_x4_kernel(const float* __restrict__ x, float* __restrict__ x4) {
  const int t = blockIdx.x;        // 0..127
  const int g = blockIdx.y;        // 0..5 (32 d4's each)
  const size_t obase = ((size_t)t * 192 + g * 32) * 128;
#pragma unroll
  for (int i = 0; i < 16; ++i) {
    int o = i * 256 + threadIdx.x;          // contiguous writes
    int d4l = o >> 7, b = (o >> 2) & 31, j = o & 3;
    x4[obase + o] = x[((size_t)b * NT + t) * ND + (g * 32 + d4l) * 4 + j];
  }
}

__global__ void init_flags_kernel(unsigned int* __restrict__ flags) {
  flags[threadIdx.x] = 0u;   // d_ws is 0xAA-poisoned each launch; must zero
}

__global__ void __launch_bounds__(NTHR, 3)
rnn_fused_kernel(const float* __restrict__ x4,
                 const float* __restrict__ wk,
                 const float* __restrict__ wrk,
                 const float* __restrict__ wak,
                 const float* __restrict__ wrak,
                 const float* __restrict__ bias,
                 const float* __restrict__ gpa,
                 const float* __restrict__ gpra,
                 const float* __restrict__ h0,   // [B,U], read at t=0
                 float* out,                     // [B,T,U]; out[b][t][u] = h_{t+1}[b][u]
                 unsigned int* flags)
{
  const int tid  = threadIdx.x;
  const int uloc = tid >> 8;       // 0..2
  const int lt   = tid & 255;
  const int b    = lt & 15;        // handles b and b+16
  const int c    = lt >> 4;        // 0..15 chunk of 48 d
  const int d0   = c * 48;
  const int u    = blockIdx.x * UPB + uloc;

  __shared__ __align__(16) float s_ak[UPB][ND], s_k[UPB][ND], s_rak[UPB][ND], s_rk[UPB][ND];
  __shared__ float red[UPB][12][4][16];
  __shared__ float s_hu[UPB][NB];                  // block-local h for own u's

#pragma unroll
  for (int j = 0; j < UPB; ++j) {
    const int ug = blockIdx.x * UPB + j;
    s_ak [j][tid] = wak [(size_t)ug * ND + tid];
    s_k  [j][tid] = wk  [(size_t)ug * ND + tid];
    s_rak[j][tid] = wrak[(size_t)ug * NU + tid];
    s_rk [j][tid] = wrk [(size_t)ug * NU + tid];
  }
  if (tid < UPB * NB) {
    const int uj = tid >> 5, bj = tid & 31;
    s_hu[uj][bj] = h0[(size_t)bj * NU + blockIdx.x * UPB + uj];
  }
  const float bias_u = bias[u];
  const float ga  = 1.0f / (1.0f + __expf(-gpa[0]));
  const float gra = 1.0f / (1.0f + __expf(-gpra[0]));
  __syncthreads();

  const float LOG2E = 1.4426950408889634f;

  for (int t = 0; t < NT; ++t) {
    // ================= x-half: needs only block-local hu =================
    const float huA = s_hu[uloc][b];
    const float huB = s_hu[uloc][b + 16];
    const float hsA = huA * LOG2E, hsB = huB * LOG2E;
    const f32x4 hsA4 = {hsA, hsA, hsA, hsA};
    const f32x4 hsB4 = {hsB, hsB, hsB, hsB};

    f32x4 saA = {0,0,0,0}, naA = {0,0,0,0}, laA = {0,0,0,0};
    f32x4 saB = {0,0,0,0}, naB = {0,0,0,0}, laB = {0,0,0,0};
    const f32x4* xp = (const f32x4*)x4 + (((size_t)t * 192 + c * 12) * 32 + b);
#pragma unroll
    for (int k4 = 0; k4 < 12; ++k4) {
      const f32x4 av  = *(const f32x4*)&s_ak[uloc][d0 + 4 * k4];
      const f32x4 kv  = *(const f32x4*)&s_k [uloc][d0 + 4 * k4];
      const f32x4 xvA = xp[k4 * 32];
      const f32x4 xvB = xp[k4 * 32 + 16];
      f32x4 tA = (xvA * av) * hsA4;
      f32x4 tB = (xvB * av) * hsB4;
      f32x4 eA = {fexp2(tA.x), fexp2(tA.y), fexp2(tA.z), fexp2(tA.w)};
      f32x4 eB = {fexp2(tB.x), fexp2(tB.y), fexp2(tB.z), fexp2(tB.w)};
      f32x4 kxA = kv * xvA;
      f32x4 kxB = kv * xvB;
      saA += eA; laA += kxA; naA += eA * kxA;
      saB += eB; laB += kxB; naB += eB * kxB;
    }
    // collapse x accumulators to 6+6 scalars (small live set across the poll)
    float v0 = saA.x + saA.y + saA.z + saA.w;
    float v1 = naA.x + naA.y + naA.z + naA.w;
    float v2 = laA.x + laA.y + laA.z + laA.w;
    float v6 = saB.x + saB.y + saB.z + saB.w;
    float v7 = naB.x + naB.y + naB.z + naB.w;
    float v8 = laB.x + laB.y + laB.z + laB.w;

    // ================= poll: everyone finished step t-1 =================
    if (t > 0) {
      if (tid < NBLK) {
        const unsigned tgt = (unsigned)t;
        while (__hip_atomic_load(&flags[tid], __ATOMIC_RELAXED, AGENT) < tgt)
          __builtin_amdgcn_s_sleep(2);
      }
      asm volatile("" ::: "memory");   // no hoisting of h reads above the poll
      __syncthreads();
    }

    // ================= r-half: h_t via normal (L2-cached) loads =================
    // h_t lives at out[.][t-1][.] (fresh lines each step; written sc1 by producers),
    // or h0 at t==0.
    const float* hsrc = (t == 0) ? h0 : out + (size_t)(t - 1) * NU;
    const size_t bstr = (t == 0) ? (size_t)NU : (size_t)NT * NU;
    const float* hpA = hsrc + (size_t)b * bstr + d0;
    const float* hpB = hsrc + (size_t)(b + 16) * bstr + d0;

    f32x4 srA = {0,0,0,0}, nrA = {0,0,0,0}, lrA = {0,0,0,0};
    f32x4 srB = {0,0,0,0}, nrB = {0,0,0,0}, lrB = {0,0,0,0};
#pragma unroll
    for (int k4 = 0; k4 < 12; ++k4) {
      const f32x4 rav = *(const f32x4*)&s_rak[uloc][d0 + 4 * k4];
      const f32x4 rkv = *(const f32x4*)&s_rk [uloc][d0 + 4 * k4];
      const f32x4 hvA = *(const f32x4*)(hpA + 4 * k4);
      const f32x4 hvB = *(const f32x4*)(hpB + 4 * k4);
      f32x4 rtA = (hvA * rav) * hsA4;
      f32x4 rtB = (hvB * rav) * hsB4;
      f32x4 reA = {fexp2(rtA.x), fexp2(rtA.y), fexp2(rtA.z), fexp2(rtA.w)};
      f32x4 reB = {fexp2(rtB.x), fexp2(rtB.y), fexp2(rtB.z), fexp2(rtB.w)};
      f32x4 khA = rkv * hvA;
      f32x4 khB = rkv * hvB;
      srA += reA; lrA += khA; nrA += reA * khA;
      srB += reB; lrB += khB; nrB += reB * khB;
    }
    float v3  = srA.x + srA.y + srA.z + srA.w;
    float v4  = nrA.x + nrA.y + nrA.z + nrA.w;
    float v5  = lrA.x + lrA.y + lrA.z + lrA.w;
    float v9  = srB.x + srB.y + srB.z + srB.w;
    float v10 = nrB.x + nrB.y + nrB.z + nrB.w;
    float v11 = lrB.x + lrB.y + lrB.z + lrB.w;

    // ================= reduce 16 chunks =================
    v0  += __shfl_xor(v0, 16);  v0  += __shfl_xor(v0, 32);
    v1  += __shfl_xor(v1, 16);  v1  += __shfl_xor(v1, 32);
    v2  += __shfl_xor(v2, 16);  v2  += __shfl_xor(v2, 32);
    v3  += __shfl_xor(v3, 16);  v3  += __shfl_xor(v3, 32);
    v4  += __shfl_xor(v4, 16);  v4  += __shfl_xor(v4, 32);
    v5  += __shfl_xor(v5, 16);  v5  += __shfl_xor(v5, 32);
    v6  += __shfl_xor(v6, 16);  v6  += __shfl_xor(v6, 32);
    v7  += __shfl_xor(v7, 16);  v7  += __shfl_xor(v7, 32);
    v8  += __shfl_xor(v8, 16);  v8  += __shfl_xor(v8, 32);
    v9  += __shfl_xor(v9, 16);  v9  += __shfl_xor(v9, 32);
    v10 += __shfl_xor(v10, 16); v10 += __shfl_xor(v10, 32);
    v11 += __shfl_xor(v11, 16); v11 += __shfl_xor(v11, 32);

    const int w = (tid >> 6) & 3;
    if ((tid & 63) < 16) {
      red[uloc][0][w][b] = v0;   red[uloc][1][w][b] = v1;   red[uloc][2][w][b] = v2;
      red[uloc][3][w][b] = v3;   red[uloc][4][w][b] = v4;   red[uloc][5][w][b] = v5;
      red[uloc][6][w][b] = v6;   red[uloc][7][w][b] = v7;   red[uloc][8][w][b] = v8;
      red[uloc][9][w][b] = v9;   red[uloc][10][w][b] = v10; red[uloc][11][w][b] = v11;
    }
    __syncthreads();

    // ================= tail: 96 threads, one output each =================
    if (lt < 32) {
      const int bb  = lt & 15;
      const int sg  = (lt < 16) ? 0 : 6;
      float r0 = red[uloc][sg+0][0][bb] + red[uloc][sg+0][1][bb] + red[uloc][sg+0][2][bb] + red[uloc][sg+0][3][bb];
      float r1 = red[uloc][sg+1][0][bb] + red[uloc][sg+1][1][bb] + red[uloc][sg+1][2][bb] + red[uloc][sg+1][3][bb];
      float r2 = red[uloc][sg+2][0][bb] + red[uloc][sg+2][1][bb] + red[uloc][sg+2][2][bb] + red[uloc][sg+2][3][bb];
      float r3 = red[uloc][sg+3][0][bb] + red[uloc][sg+3][1][bb] + red[uloc][sg+3][2][bb] + red[uloc][sg+3][3][bb];
      float r4 = red[uloc][sg+4][0][bb] + red[uloc][sg+4][1][bb] + red[uloc][sg+4][2][bb] + red[uloc][sg+4][3][bb];
      float r5 = red[uloc][sg+5][0][bb] + red[uloc][sg+5][1][bb] + red[uloc][sg+5][2][bb] + red[uloc][sg+5][3][bb];
      float hh = r2 + bias_u + ga * (r1 * frcp(r0));
      float z  = hh + r5 + gra * (r4 * frcp(r3));
      float ex = fexp2(z * 2.8853900817779268f);   // tanh(z) = 1 - 2/(e^{2z}+1)
      float o  = 1.0f - 2.0f * frcp(ex + 1.0f);
      // h_{t+1}[lt][u] == out[lt][t][u]
      __hip_atomic_store(&out[((size_t)lt * NT + t) * NU + u], o, __ATOMIC_RELAXED, AGENT);
      s_hu[uloc][lt] = o;
    }

    if (t != NT - 1) {
      asm volatile("s_waitcnt vmcnt(0)" ::: "memory");
      __syncthreads();   // all three tail waves' h-stores drained; s_hu visible
      if (tid == 0)
        __hip_atomic_store(&flags[blockIdx.x], (unsigned)(t + 1), __ATOMIC_RELAXED, AGENT);
    }
  }
}

extern "C" void kernel_launch(void* const* d_in, const int* in_sizes, int n_in,
                              void* d_out, int out_size, void* d_ws, size_t ws_size,
                              hipStream_t stream) {
  const float* x    = (const float*)d_in[0];
  const float* h0   = (const float*)d_in[1];
  const float* wk   = (const float*)d_in[2];
  const float* wrk  = (const float*)d_in[3];
  const float* wak  = (const float*)d_in[4];
  const float* wrak = (const float*)d_in[5];
  const float* bias = (const float*)d_in[6];
  const float* gpa  = (const float*)d_in[7];
  const float* gpra = (const float*)d_in[8];
  float* out = (float*)d_out;

  float* x4 = (float*)d_ws;                         // 12.58 MB
  unsigned int* flags = (unsigned int*)(x4 + (size_t)NT * ND * NB);

  make_x4_kernel<<<dim3(NT, 6), 256, 0, stream>>>(x, x4);
  init_flags_kernel<<<1, 256, 0, stream>>>(flags);
  rnn_fused_kernel<<<NBLK, NTHR, 0, stream>>>(x4, wk, wrk, wak, wrak, bias, gpa, gpra,
                                              h0, out, flags);
}